// Round 7
// baseline (476.075 us; speedup 1.0000x reference)
//
#include <hip/hip_runtime.h>

#define NB 32
#define NPTS 1024
#define NP 256
#define NS 16
#define NC 256
#define NH 128
#define NOUT 97
#define RP 20   // padded LDS row stride (floats): 80B, 16B-aligned, bank-spread

// ---------------------------------------------------------------------------
// Prep. Lane-split weight layouts for the 4-o-per-lane / c-split-2 scheme:
//   wl[(c*32+og)*4+k] = W[og+32k][c]   (one dwordx4 per (c, o-group))
// ---------------------------------------------------------------------------
__global__ __launch_bounds__(256) void prep_kernel(
    const float* __restrict__ sa_w0, const float* __restrict__ sa_w1,
    const float* __restrict__ sa_w2, const float* __restrict__ fc_w1,
    const float* __restrict__ fc_w2, const float* __restrict__ fc_w3,
    float* __restrict__ w0l, float* __restrict__ w0x,
    float* __restrict__ wl1, float* __restrict__ wl2,
    float* __restrict__ fl1, float* __restrict__ fl2,
    float* __restrict__ fl3)
{
  int t = blockIdx.x * 256 + threadIdx.x;
  if (t >= 256 * 128) return;
  int c = t >> 7, o = t & 127;
  int og = o & 31, k = o >> 5;
  w0l[(c * 32 + og) * 4 + k] = sa_w0[o * 259 + 3 + c];
  if (c < 3) w0x[c * 128 + o] = sa_w0[o * 259 + c];
  if (c < 128) {
    int qi = (c * 32 + og) * 4 + k;
    wl1[qi] = sa_w1[o * 128 + c];
    wl2[qi] = sa_w2[o * 128 + c];
    fl1[qi] = fc_w1[o * 128 + c];
    fl2[qi] = fc_w2[o * 128 + c];
    fl3[qi] = (o < NOUT) ? fc_w3[o * 128 + c] : 0.0f;
  }
}

// pair-add across lanes l <-> l^1 via DPP quad_perm [1,0,3,2] (VALU, no LDS)
__device__ __forceinline__ float dpp_pair_add(float v) {
  float ov = __int_as_float(
      __builtin_amdgcn_mov_dpp(__float_as_int(v), 0xB1, 0xF, 0xF, true));
  return v + ov;
}

// ---------------------------------------------------------------------------
// Fused FPS + gfeat, 64-thread (1-wave) blocks.
//   blocks [0, NB):       FPS, one wave per batch. u64 key (hi=dist bits,
//                         lo=1023-idx) -> max == first-max.
//   blocks [NB, NB+2048): G[b][n][o] = sum_c features[b][c][n] * w0[o][3+c].
// All register arrays statically indexed (rule #20: runtime idx -> scratch).
// ---------------------------------------------------------------------------
__global__ __launch_bounds__(64) void fused_fps_gfeat_kernel(
    const float* __restrict__ xyz, int* __restrict__ inds,
    const float* __restrict__ features, const float* __restrict__ w0l,
    float* __restrict__ G)
{
  __shared__ __align__(16) float smem[NC * RP];   // 20 KB
  const int lane = threadIdx.x;

  if (blockIdx.x < NB) {
    // ------------------------- FPS -------------------------
    const int b = blockIdx.x;
    const float* xb = xyz + b * NPTS * 3;
    float pts[48];
    const float4* src = reinterpret_cast<const float4*>(xb + lane * 48);
#pragma unroll
    for (int r = 0; r < 12; ++r) {
      float4 v = src[r];
      pts[4 * r + 0] = v.x; pts[4 * r + 1] = v.y;
      pts[4 * r + 2] = v.z; pts[4 * r + 3] = v.w;
      *reinterpret_cast<float4*>(smem + lane * 48 + 4 * r) = v;   // raw mirror
    }
    float dist[16];
#pragma unroll
    for (int j = 0; j < 16; ++j) dist[j] = 1e10f;
    int far = 0;
    for (int i = 0; i < NP; ++i) {
      if (lane == 0) inds[b * NP + i] = far;
      float cx = smem[far * 3 + 0], cy = smem[far * 3 + 1], cz = smem[far * 3 + 2];
      unsigned long long bk = 0ull;
#pragma unroll
      for (int j = 0; j < 16; ++j) {
#pragma clang fp contract(off)
        float dx = pts[3 * j + 0] - cx;
        float dy = pts[3 * j + 1] - cy;
        float dz = pts[3 * j + 2] - cz;
        float d = (dx * dx + dy * dy) + dz * dz;
        float nd = fminf(dist[j], d);
        dist[j] = nd;
        unsigned long long key =
            ((unsigned long long)__float_as_uint(nd) << 32)
            | (unsigned)(1023 - (lane * 16 + j));
        bk = (key > bk) ? key : bk;
      }
      unsigned hi = (unsigned)(bk >> 32), lo = (unsigned)bk;
      {
        unsigned ohi = (unsigned)__builtin_amdgcn_mov_dpp((int)hi, 0xB1, 0xF, 0xF, true);
        unsigned olo = (unsigned)__builtin_amdgcn_mov_dpp((int)lo, 0xB1, 0xF, 0xF, true);
        if (ohi > hi || (ohi == hi && olo > lo)) { hi = ohi; lo = olo; }
      }
      {
        unsigned ohi = (unsigned)__builtin_amdgcn_mov_dpp((int)hi, 0x4E, 0xF, 0xF, true);
        unsigned olo = (unsigned)__builtin_amdgcn_mov_dpp((int)lo, 0x4E, 0xF, 0xF, true);
        if (ohi > hi || (ohi == hi && olo > lo)) { hi = ohi; lo = olo; }
      }
      {
        unsigned ohi = (unsigned)__builtin_amdgcn_ds_swizzle((int)hi, 0x101F);
        unsigned olo = (unsigned)__builtin_amdgcn_ds_swizzle((int)lo, 0x101F);
        if (ohi > hi || (ohi == hi && olo > lo)) { hi = ohi; lo = olo; }
      }
      {
        unsigned ohi = (unsigned)__builtin_amdgcn_ds_swizzle((int)hi, 0x201F);
        unsigned olo = (unsigned)__builtin_amdgcn_ds_swizzle((int)lo, 0x201F);
        if (ohi > hi || (ohi == hi && olo > lo)) { hi = ohi; lo = olo; }
      }
      {
        unsigned ohi = (unsigned)__builtin_amdgcn_ds_swizzle((int)hi, 0x401F);
        unsigned olo = (unsigned)__builtin_amdgcn_ds_swizzle((int)lo, 0x401F);
        if (ohi > hi || (ohi == hi && olo > lo)) { hi = ohi; lo = olo; }
      }
      {
        unsigned ohi = (unsigned)__shfl_xor((int)hi, 32);
        unsigned olo = (unsigned)__shfl_xor((int)lo, 32);
        if (ohi > hi || (ohi == hi && olo > lo)) { hi = ohi; lo = olo; }
      }
      far = 1023 - (int)lo;
    }
    return;
  }

  // ------------------------- gfeat -------------------------
  const int blk = blockIdx.x - NB;
  const int b  = blk >> 6;
  const int n0 = (blk & 63) * 16;
  const int og = lane >> 1;
  const int cg = lane & 1;
  const float* fb = features + b * NC * NPTS;
#pragma unroll
  for (int r = 0; r < 4; ++r) {
    int c = r * 64 + lane;
    const float4* s4 = reinterpret_cast<const float4*>(fb + c * NPTS + n0);
    float4 v0 = s4[0], v1 = s4[1], v2 = s4[2], v3 = s4[3];
    float* row = smem + c * RP;
    reinterpret_cast<float4*>(row)[0] = v0;
    reinterpret_cast<float4*>(row)[1] = v1;
    reinterpret_cast<float4*>(row)[2] = v2;
    reinterpret_cast<float4*>(row)[3] = v3;
  }
  // single wave: LDS ops execute in program order; compiler inserts lgkmcnt.
  float acc[4][16];
#pragma unroll
  for (int k = 0; k < 4; ++k)
#pragma unroll
    for (int j = 0; j < 16; ++j) acc[k][j] = 0.0f;
  const int cbase = cg * 128;
#pragma unroll 2
  for (int cl = 0; cl < 128; ++cl) {
    int c = cbase + cl;
    const float4 wq = *reinterpret_cast<const float4*>(w0l + (c * 32 + og) * 4);
    const float* row = smem + c * RP;
    const float4 x0 = reinterpret_cast<const float4*>(row)[0];
    const float4 x1 = reinterpret_cast<const float4*>(row)[1];
    const float4 x2 = reinterpret_cast<const float4*>(row)[2];
    const float4 x3 = reinterpret_cast<const float4*>(row)[3];
    const float wk[4] = {wq.x, wq.y, wq.z, wq.w};
    const float xr[16] = {x0.x, x0.y, x0.z, x0.w, x1.x, x1.y, x1.z, x1.w,
                          x2.x, x2.y, x2.z, x2.w, x3.x, x3.y, x3.z, x3.w};
#pragma unroll
    for (int k = 0; k < 4; ++k)
#pragma unroll
      for (int j = 0; j < 16; ++j)
        acc[k][j] = fmaf(wk[k], xr[j], acc[k][j]);
  }
#pragma unroll
  for (int k = 0; k < 4; ++k)
#pragma unroll
    for (int j = 0; j < 16; ++j) acc[k][j] = dpp_pair_add(acc[k][j]);
  // store: lane (og,cg) stores o = og+32*(2cg+m), m=0,1 — STATIC acc indices
#pragma unroll
  for (int m = 0; m < 2; ++m) {
    int o = og + 32 * (cg * 2 + m);
    float* gp = G + (b * NPTS + n0) * NH + o;
#pragma unroll
    for (int j = 0; j < 16; ++j) {
      float v = cg ? acc[m + 2][j] : acc[m][j];   // static idx + cndmask
      gp[j * NH] = v;
    }
  }
}

// ---------------------------------------------------------------------------
// Main kernel: 128-thread blocks = 2 independent waves, each wave owns one
// (b,p) tile. No __syncthreads (wave-lockstep LDS ordering).
// lane=(og=lane>>1, cg=lane&1): 4 o's per lane, 64-c half; DPP pair-add
// merges c-halves. X tile in LDS, padded rows of RP floats.
// All register arrays statically indexed (rule #20).
// ---------------------------------------------------------------------------
__global__ __launch_bounds__(128) void main_kernel(
    const float* __restrict__ xyz, const int* __restrict__ inds,
    const float* __restrict__ G,
    const float* __restrict__ w0x, const float* __restrict__ s0v, const float* __restrict__ t0v,
    const float* __restrict__ wl1, const float* __restrict__ s1v, const float* __restrict__ t1v,
    const float* __restrict__ wl2, const float* __restrict__ s2v, const float* __restrict__ t2v,
    const float* __restrict__ fl1, const float* __restrict__ fs1, const float* __restrict__ ft1,
    const float* __restrict__ fl2, const float* __restrict__ fs2, const float* __restrict__ ft2,
    const float* __restrict__ fl3, const float* __restrict__ b3, float* __restrict__ out)
{
  __shared__ __align__(16) float xt[2][NH * RP];   // 20 KB (2 waves)
  __shared__ float gxs[2][NS][3];
  __shared__ int   idxs[2][NS];

  const int w    = threadIdx.x >> 6;
  const int lane = threadIdx.x & 63;
  const int bid  = blockIdx.x * 2 + w;            // == b*NP + p
  const int b = bid >> 8;
  const int p = bid & 255;
  const int og = lane >> 1;
  const int cg = lane & 1;
  const int cb = cg * 64;

  const float* xb = xyz + b * NPTS * 3;
  float* xs = &xt[w][0];

  // ---- ball query (bit-identical to reference), one wave ----
  {
    const int ci = inds[bid];
    const float cx = xb[ci * 3 + 0], cy = xb[ci * 3 + 1], cz = xb[ci * 3 + 2];
    float nq;
    {
#pragma clang fp contract(off)
      nq = (cx * cx + cy * cy) + cz * cz;
    }
    const float R2 = 0.09f;
    unsigned mask = 0;
    int cnt = 0, firstn = NPTS;
    for (int j = 0; j < 16; ++j) {
#pragma clang fp contract(off)
      int n = lane * 16 + j;   // lane-major: global order == lexicographic
      float x = xb[n * 3 + 0], y = xb[n * 3 + 1], z = xb[n * 3 + 2];
      float nx = (x * x + y * y) + z * z;
      float dt = (cx * x + cy * y) + cz * z;
      float d2 = (nq + nx) - 2.0f * dt;
      if (d2 < R2) { mask |= 1u << j; ++cnt; if (firstn == NPTS) firstn = n; }
    }
    int inc = cnt;
    for (int off = 1; off < 64; off <<= 1) {
      int v = __shfl_up(inc, off);
      if (lane >= off) inc += v;
    }
    int rank  = inc - cnt;
    int total = __shfl(inc, 63);
    for (int j = 0; j < 16; ++j) {
      if (mask & (1u << j)) {
        if (rank < NS) {
          int n = lane * 16 + j;
          idxs[w][rank] = n;
          float x = xb[n * 3 + 0], y = xb[n * 3 + 1], z = xb[n * 3 + 2];
          gxs[w][rank][0] = (x - cx) / 0.3f;
          gxs[w][rank][1] = (y - cy) / 0.3f;
          gxs[w][rank][2] = (z - cz) / 0.3f;
        }
        ++rank;
      }
    }
    int fmin = firstn;
    for (int off2 = 32; off2 > 0; off2 >>= 1) {
      int ov = __shfl_xor(fmin, off2);
      fmin = min(fmin, ov);
    }
    if (lane < NS && lane >= total) {
      idxs[w][lane] = fmin;
      float x = xb[fmin * 3 + 0], y = xb[fmin * 3 + 1], z = xb[fmin * 3 + 2];
      gxs[w][lane][0] = (x - cx) / 0.3f;
      gxs[w][lane][1] = (y - cy) / 0.3f;
      gxs[w][lane][2] = (z - cz) / 0.3f;
    }
  }

  // ---- L0: lane computes x1 rows (lane) and (lane+64) ----
  {
    const float wa0 = w0x[lane],      wb0 = w0x[128 + lane],      wc0 = w0x[256 + lane];
    const float wa1 = w0x[lane + 64], wb1 = w0x[128 + lane + 64], wc1 = w0x[256 + lane + 64];
    const float ss0 = s0v[lane], tt0 = t0v[lane];
    const float ss1 = s0v[lane + 64], tt1 = t0v[lane + 64];
    float r0[16], r1[16];
#pragma unroll
    for (int j = 0; j < 16; ++j) {
      int nj = idxs[w][j];
      float gx = gxs[w][j][0], gy = gxs[w][j][1], gz = gxs[w][j][2];
      const float* gp = G + (b * NPTS + nj) * NH;
      float g0 = gp[lane], g1 = gp[lane + 64];
      float y0 = fmaf(wa0, gx, fmaf(wb0, gy, fmaf(wc0, gz, g0)));
      float y1 = fmaf(wa1, gx, fmaf(wb1, gy, fmaf(wc1, gz, g1)));
      r0[j] = fmaxf(fmaf(y0, ss0, tt0), 0.0f);
      r1[j] = fmaxf(fmaf(y1, ss1, tt1), 0.0f);
    }
    float* rowA = xs + lane * RP;
    float* rowB = xs + (lane + 64) * RP;
#pragma unroll
    for (int q = 0; q < 4; ++q) {
      reinterpret_cast<float4*>(rowA)[q] =
          make_float4(r0[4 * q], r0[4 * q + 1], r0[4 * q + 2], r0[4 * q + 3]);
      reinterpret_cast<float4*>(rowB)[q] =
          make_float4(r1[4 * q], r1[4 * q + 1], r1[4 * q + 2], r1[4 * q + 3]);
    }
  }

  float acc[4][16];

  // ---- L1 ----
#pragma unroll
  for (int k = 0; k < 4; ++k)
#pragma unroll
    for (int j = 0; j < 16; ++j) acc[k][j] = 0.0f;
#pragma unroll 2
  for (int cl = 0; cl < 64; ++cl) {
    int c = cb + cl;
    const float4 wq = *reinterpret_cast<const float4*>(wl1 + (c * 32 + og) * 4);
    const float* row = xs + c * RP;
    const float4 x0 = reinterpret_cast<const float4*>(row)[0];
    const float4 x1 = reinterpret_cast<const float4*>(row)[1];
    const float4 x2 = reinterpret_cast<const float4*>(row)[2];
    const float4 x3 = reinterpret_cast<const float4*>(row)[3];
    const float wk[4] = {wq.x, wq.y, wq.z, wq.w};
    const float xr[16] = {x0.x, x0.y, x0.z, x0.w, x1.x, x1.y, x1.z, x1.w,
                          x2.x, x2.y, x2.z, x2.w, x3.x, x3.y, x3.z, x3.w};
#pragma unroll
    for (int k = 0; k < 4; ++k)
#pragma unroll
      for (int j = 0; j < 16; ++j)
        acc[k][j] = fmaf(wk[k], xr[j], acc[k][j]);
  }
#pragma unroll
  for (int k = 0; k < 4; ++k)
#pragma unroll
    for (int j = 0; j < 16; ++j) acc[k][j] = dpp_pair_add(acc[k][j]);
  // BN+ReLU, write x2 rows — STATIC acc indices (cndmask select on cg)
#pragma unroll
  for (int m = 0; m < 2; ++m) {
    int o = og + 32 * (cg * 2 + m);
    const float ss = s1v[o], tt = t1v[o];
    float r[16];
#pragma unroll
    for (int j = 0; j < 16; ++j) {
      float v = cg ? acc[m + 2][j] : acc[m][j];
      r[j] = fmaxf(fmaf(v, ss, tt), 0.0f);
    }
    float* row = xs + o * RP;
#pragma unroll
    for (int q = 0; q < 4; ++q)
      reinterpret_cast<float4*>(row)[q] =
          make_float4(r[4 * q], r[4 * q + 1], r[4 * q + 2], r[4 * q + 3]);
  }

  // ---- L2 + maxpool ----
#pragma unroll
  for (int k = 0; k < 4; ++k)
#pragma unroll
    for (int j = 0; j < 16; ++j) acc[k][j] = 0.0f;
#pragma unroll 2
  for (int cl = 0; cl < 64; ++cl) {
    int c = cb + cl;
    const float4 wq = *reinterpret_cast<const float4*>(wl2 + (c * 32 + og) * 4);
    const float* row = xs + c * RP;
    const float4 x0 = reinterpret_cast<const float4*>(row)[0];
    const float4 x1 = reinterpret_cast<const float4*>(row)[1];
    const float4 x2 = reinterpret_cast<const float4*>(row)[2];
    const float4 x3 = reinterpret_cast<const float4*>(row)[3];
    const float wk[4] = {wq.x, wq.y, wq.z, wq.w};
    const float xr[16] = {x0.x, x0.y, x0.z, x0.w, x1.x, x1.y, x1.z, x1.w,
                          x2.x, x2.y, x2.z, x2.w, x3.x, x3.y, x3.z, x3.w};
#pragma unroll
    for (int k = 0; k < 4; ++k)
#pragma unroll
      for (int j = 0; j < 16; ++j)
        acc[k][j] = fmaf(wk[k], xr[j], acc[k][j]);
  }
#pragma unroll
  for (int k = 0; k < 4; ++k)
#pragma unroll
    for (int j = 0; j < 16; ++j) acc[k][j] = dpp_pair_add(acc[k][j]);
  // BN+ReLU+max over j; f -> xs[0..127] — STATIC acc indices
#pragma unroll
  for (int m = 0; m < 2; ++m) {
    int o = og + 32 * (cg * 2 + m);
    const float ss = s2v[o], tt = t2v[o];
    float fo = 0.0f;
#pragma unroll
    for (int j = 0; j < 16; ++j) {
      float v = cg ? acc[m + 2][j] : acc[m][j];
      fo = fmaxf(fo, fmaxf(fmaf(v, ss, tt), 0.0f));
    }
    xs[o] = fo;
  }

  // ---- FC1: h (xs[128..255]) = relu(bn(fw1 @ f)) ----
  {
    float h4[4] = {0.0f, 0.0f, 0.0f, 0.0f};
#pragma unroll 4
    for (int cl = 0; cl < 64; ++cl) {
      int c = cb + cl;
      const float fvv = xs[c];
      const float4 wq = *reinterpret_cast<const float4*>(fl1 + (c * 32 + og) * 4);
      h4[0] = fmaf(wq.x, fvv, h4[0]);
      h4[1] = fmaf(wq.y, fvv, h4[1]);
      h4[2] = fmaf(wq.z, fvv, h4[2]);
      h4[3] = fmaf(wq.w, fvv, h4[3]);
    }
#pragma unroll
    for (int k = 0; k < 4; ++k) h4[k] = dpp_pair_add(h4[k]);
#pragma unroll
    for (int m = 0; m < 2; ++m) {
      int o = og + 32 * (cg * 2 + m);
      float hv = cg ? h4[m + 2] : h4[m];          // static idx
      xs[128 + o] = fmaxf(fmaf(hv, fs1[o], ft1[o]), 0.0f);
    }
  }

  // ---- FC2: f2 (xs[0..127]) = relu(bn(fw2 @ h)) ----
  {
    float h4[4] = {0.0f, 0.0f, 0.0f, 0.0f};
#pragma unroll 4
    for (int cl = 0; cl < 64; ++cl) {
      int c = cb + cl;
      const float fvv = xs[128 + c];
      const float4 wq = *reinterpret_cast<const float4*>(fl2 + (c * 32 + og) * 4);
      h4[0] = fmaf(wq.x, fvv, h4[0]);
      h4[1] = fmaf(wq.y, fvv, h4[1]);
      h4[2] = fmaf(wq.z, fvv, h4[2]);
      h4[3] = fmaf(wq.w, fvv, h4[3]);
    }
#pragma unroll
    for (int k = 0; k < 4; ++k) h4[k] = dpp_pair_add(h4[k]);
#pragma unroll
    for (int m = 0; m < 2; ++m) {
      int o = og + 32 * (cg * 2 + m);
      float hv = cg ? h4[m + 2] : h4[m];
      xs[o] = fmaxf(fmaf(hv, fs2[o], ft2[o]), 0.0f);
    }
  }

  // ---- FC3 ----
  {
    float h4[4] = {0.0f, 0.0f, 0.0f, 0.0f};
#pragma unroll 4
    for (int cl = 0; cl < 64; ++cl) {
      int c = cb + cl;
      const float fvv = xs[c];
      const float4 wq = *reinterpret_cast<const float4*>(fl3 + (c * 32 + og) * 4);
      h4[0] = fmaf(wq.x, fvv, h4[0]);
      h4[1] = fmaf(wq.y, fvv, h4[1]);
      h4[2] = fmaf(wq.z, fvv, h4[2]);
      h4[3] = fmaf(wq.w, fvv, h4[3]);
    }
#pragma unroll
    for (int k = 0; k < 4; ++k) h4[k] = dpp_pair_add(h4[k]);
#pragma unroll
    for (int m = 0; m < 2; ++m) {
      int o = og + 32 * (cg * 2 + m);
      float hv = cg ? h4[m + 2] : h4[m];
      if (o < NOUT) out[(b * NOUT + o) * NP + p] = hv + b3[o];
    }
  }
}

extern "C" void kernel_launch(void* const* d_in, const int* in_sizes, int n_in,
                              void* d_out, int out_size, void* d_ws, size_t ws_size,
                              hipStream_t stream) {
  const float* xyz      = (const float*)d_in[0];
  const float* features = (const float*)d_in[1];
  const float* sa_w0 = (const float*)d_in[2];
  const float* sa_s0 = (const float*)d_in[3];
  const float* sa_t0 = (const float*)d_in[4];
  const float* sa_w1 = (const float*)d_in[5];
  const float* sa_s1 = (const float*)d_in[6];
  const float* sa_t1 = (const float*)d_in[7];
  const float* sa_w2 = (const float*)d_in[8];
  const float* sa_s2 = (const float*)d_in[9];
  const float* sa_t2 = (const float*)d_in[10];
  const float* fc_w1 = (const float*)d_in[11];
  const float* fc_s1 = (const float*)d_in[12];
  const float* fc_t1 = (const float*)d_in[13];
  const float* fc_w2 = (const float*)d_in[14];
  const float* fc_s2 = (const float*)d_in[15];
  const float* fc_t2 = (const float*)d_in[16];
  const float* fc_w3 = (const float*)d_in[17];
  const float* fc_b3 = (const float*)d_in[18];
  float* out = (float*)d_out;

  char* ws = (char*)d_ws;
  int* inds = (int*)ws;            ws += (size_t)NB * NP * sizeof(int);
  float* w0l  = (float*)ws;        ws += (size_t)256 * 128 * sizeof(float);
  float* w0x  = (float*)ws;        ws += (size_t)3 * 128 * sizeof(float);
  float* wl1  = (float*)ws;        ws += (size_t)128 * 128 * sizeof(float);
  float* wl2  = (float*)ws;        ws += (size_t)128 * 128 * sizeof(float);
  float* fl1  = (float*)ws;        ws += (size_t)128 * 128 * sizeof(float);
  float* fl2  = (float*)ws;        ws += (size_t)128 * 128 * sizeof(float);
  float* fl3  = (float*)ws;        ws += (size_t)128 * 128 * sizeof(float);
  float* G    = (float*)ws;        ws += (size_t)NB * NPTS * NH * sizeof(float);

  prep_kernel<<<128, 256, 0, stream>>>(sa_w0, sa_w1, sa_w2, fc_w1, fc_w2, fc_w3,
                                       w0l, w0x, wl1, wl2, fl1, fl2, fl3);
  fused_fps_gfeat_kernel<<<NB + NB * (NPTS / 16), 64, 0, stream>>>(
      xyz, inds, features, w0l, G);
  main_kernel<<<NB * NP / 2, 128, 0, stream>>>(
      xyz, inds, G,
      w0x, sa_s0, sa_t0,
      wl1, sa_s1, sa_t1,
      wl2, sa_s2, sa_t2,
      fl1, fc_s1, fc_t1,
      fl2, fc_s2, fc_t2,
      fl3, fc_b3, out);
}

// Round 8
// 391.976 us; speedup vs baseline: 1.2145x; 1.2145x over previous
//
#include <hip/hip_runtime.h>

#define NB 32
#define NPTS 1024
#define NP 256
#define NS 16
#define NC 256
#define NH 128
#define NOUT 97
#define RP 20   // padded LDS row stride (floats): 80B, 16B-aligned

// ---------------------------------------------------------------------------
// Prep. Lane-split weight layouts: wl[(c*32+og)*4+k] = W[og+32k][c]
// (one dwordx4 per (c, o-group)). w0x[d*128+o] = sa_w0[o][d].
// ---------------------------------------------------------------------------
__global__ __launch_bounds__(256) void prep_kernel(
    const float* __restrict__ sa_w0, const float* __restrict__ sa_w1,
    const float* __restrict__ sa_w2, const float* __restrict__ fc_w1,
    const float* __restrict__ fc_w2, const float* __restrict__ fc_w3,
    float* __restrict__ w0l, float* __restrict__ w0x,
    float* __restrict__ wl1, float* __restrict__ wl2,
    float* __restrict__ fl1, float* __restrict__ fl2,
    float* __restrict__ fl3)
{
  int t = blockIdx.x * 256 + threadIdx.x;
  if (t >= 256 * 128) return;
  int c = t >> 7, o = t & 127;
  int og = o & 31, k = o >> 5;
  w0l[(c * 32 + og) * 4 + k] = sa_w0[o * 259 + 3 + c];
  if (c < 3) w0x[c * 128 + o] = sa_w0[o * 259 + c];
  if (c < 128) {
    int qi = (c * 32 + og) * 4 + k;
    wl1[qi] = sa_w1[o * 128 + c];
    wl2[qi] = sa_w2[o * 128 + c];
    fl1[qi] = fc_w1[o * 128 + c];
    fl2[qi] = fc_w2[o * 128 + c];
    fl3[qi] = (o < NOUT) ? fc_w3[o * 128 + c] : 0.0f;
  }
}

// ---------------------------------------------------------------------------
// Fused FPS + gfeat, 64-thread (1-wave) blocks.
//   blocks [0, NB):       FPS. px/py/dist in regs (48), z in padded LDS SoA
//                         (idx = lane*17+j, conflict-free) -> peak VGPR < 64.
//   blocks [NB, NB+2048): gfeat, j-split: lane=(og,jg), acc[4][8] (32 regs),
//                         full-c per lane, no cross-lane combine.
// ---------------------------------------------------------------------------
__global__ __launch_bounds__(64) void fused_fps_gfeat_kernel(
    const float* __restrict__ xyz, int* __restrict__ inds,
    const float* __restrict__ features, const float* __restrict__ w0l,
    float* __restrict__ G)
{
  __shared__ __align__(16) float smem[NC * RP];   // 20 KB
  const int lane = threadIdx.x;

  if (blockIdx.x < NB) {
    // ------------------------- FPS -------------------------
    const int b = blockIdx.x;
    const float* xb = xyz + b * NPTS * 3;
    float* s_xp = smem;
    float* s_yp = smem + 1088;
    float* s_zp = smem + 2176;
    const int pbase = lane * 17;
    float px[16], py[16], dist[16];
    const float4* src = reinterpret_cast<const float4*>(xb + lane * 48);
#pragma unroll
    for (int q = 0; q < 4; ++q) {
      float4 v0 = src[3 * q], v1 = src[3 * q + 1], v2 = src[3 * q + 2];
      const float xv[4] = {v0.x, v0.w, v1.z, v2.y};
      const float yv[4] = {v0.y, v1.x, v1.w, v2.z};
      const float zv[4] = {v0.z, v1.y, v2.x, v2.w};
#pragma unroll
      for (int t = 0; t < 4; ++t) {
        px[4 * q + t] = xv[t];
        py[4 * q + t] = yv[t];
        s_xp[pbase + 4 * q + t] = xv[t];
        s_yp[pbase + 4 * q + t] = yv[t];
        s_zp[pbase + 4 * q + t] = zv[t];
      }
    }
#pragma unroll
    for (int j = 0; j < 16; ++j) dist[j] = 1e10f;
    int far = 0;
    for (int i = 0; i < NP; ++i) {
      if (lane == 0) inds[b * NP + i] = far;
      int cidx = far + (far >> 4);
      float cx = s_xp[cidx], cy = s_yp[cidx], cz = s_zp[cidx];
      float bv = -1.0f; int bi = 0;
#pragma unroll
      for (int j = 0; j < 16; ++j) {
#pragma clang fp contract(off)
        float pz = s_zp[pbase + j];
        float dx = px[j] - cx;
        float dy = py[j] - cy;
        float dz = pz - cz;
        float d = (dx * dx + dy * dy) + dz * dz;
        float nd = fminf(dist[j], d);
        dist[j] = nd;
        if (nd > bv) { bv = nd; bi = j; }   // ascending j -> first max
      }
      unsigned hi = __float_as_uint(bv);             // bv >= 0: f32 order == u32
      unsigned lo = (unsigned)(1023 - (lane * 16 + bi));
      {
        unsigned ohi = (unsigned)__builtin_amdgcn_mov_dpp((int)hi, 0xB1, 0xF, 0xF, true);
        unsigned olo = (unsigned)__builtin_amdgcn_mov_dpp((int)lo, 0xB1, 0xF, 0xF, true);
        if (ohi > hi || (ohi == hi && olo > lo)) { hi = ohi; lo = olo; }
      }
      {
        unsigned ohi = (unsigned)__builtin_amdgcn_mov_dpp((int)hi, 0x4E, 0xF, 0xF, true);
        unsigned olo = (unsigned)__builtin_amdgcn_mov_dpp((int)lo, 0x4E, 0xF, 0xF, true);
        if (ohi > hi || (ohi == hi && olo > lo)) { hi = ohi; lo = olo; }
      }
      {
        unsigned ohi = (unsigned)__builtin_amdgcn_ds_swizzle((int)hi, 0x101F);
        unsigned olo = (unsigned)__builtin_amdgcn_ds_swizzle((int)lo, 0x101F);
        if (ohi > hi || (ohi == hi && olo > lo)) { hi = ohi; lo = olo; }
      }
      {
        unsigned ohi = (unsigned)__builtin_amdgcn_ds_swizzle((int)hi, 0x201F);
        unsigned olo = (unsigned)__builtin_amdgcn_ds_swizzle((int)lo, 0x201F);
        if (ohi > hi || (ohi == hi && olo > lo)) { hi = ohi; lo = olo; }
      }
      {
        unsigned ohi = (unsigned)__builtin_amdgcn_ds_swizzle((int)hi, 0x401F);
        unsigned olo = (unsigned)__builtin_amdgcn_ds_swizzle((int)lo, 0x401F);
        if (ohi > hi || (ohi == hi && olo > lo)) { hi = ohi; lo = olo; }
      }
      {
        unsigned ohi = (unsigned)__shfl_xor((int)hi, 32);
        unsigned olo = (unsigned)__shfl_xor((int)lo, 32);
        if (ohi > hi || (ohi == hi && olo > lo)) { hi = ohi; lo = olo; }
      }
      far = 1023 - (int)lo;
    }
    return;
  }

  // ------------------------- gfeat (j-split) -------------------------
  const int blk = blockIdx.x - NB;
  const int b  = blk >> 6;
  const int n0 = (blk & 63) * 16;
  const int og = lane & 31;
  const int jg = lane >> 5;
  const int joff = jg * 8;
  const float* fb = features + b * NC * NPTS;
#pragma unroll
  for (int r = 0; r < 4; ++r) {
    int c = r * 64 + lane;
    const float4* s4 = reinterpret_cast<const float4*>(fb + c * NPTS + n0);
    float4 v0 = s4[0], v1 = s4[1], v2 = s4[2], v3 = s4[3];
    float* row = smem + c * RP;
    reinterpret_cast<float4*>(row)[0] = v0;
    reinterpret_cast<float4*>(row)[1] = v1;
    reinterpret_cast<float4*>(row)[2] = v2;
    reinterpret_cast<float4*>(row)[3] = v3;
  }
  // single wave: LDS write->read ordered in-wave by lgkmcnt.
  float acc[4][8];
#pragma unroll
  for (int k = 0; k < 4; ++k)
#pragma unroll
    for (int nn = 0; nn < 8; ++nn) acc[k][nn] = 0.0f;
#pragma unroll 2
  for (int c = 0; c < NC; ++c) {
    const float4 wq = *reinterpret_cast<const float4*>(w0l + (c * 32 + og) * 4);
    const float* row = smem + c * RP + joff;
    const float4 xa = reinterpret_cast<const float4*>(row)[0];
    const float4 xb4 = reinterpret_cast<const float4*>(row)[1];
    const float wk[4] = {wq.x, wq.y, wq.z, wq.w};
    const float xr[8] = {xa.x, xa.y, xa.z, xa.w, xb4.x, xb4.y, xb4.z, xb4.w};
#pragma unroll
    for (int k = 0; k < 4; ++k)
#pragma unroll
      for (int nn = 0; nn < 8; ++nn)
        acc[k][nn] = fmaf(wk[k], xr[nn], acc[k][nn]);
  }
#pragma unroll
  for (int k = 0; k < 4; ++k) {
    int o = og + 32 * k;
    float* gp = G + ((size_t)(b * NPTS + n0 + joff)) * NH + o;
#pragma unroll
    for (int nn = 0; nn < 8; ++nn) gp[nn * NH] = acc[k][nn];
  }
}

// ---------------------------------------------------------------------------
// Main kernel: 128-thread blocks = 2 independent waves, each wave owns one
// (b,p) tile. No __syncthreads (wave-lockstep LDS ordering).
// j-split: lane=(og=lane&31, jg=lane>>5); acc[4][8] (32 regs), full c per
// lane; maxpool/FC merge via one shfl_xor(32). X tile rows RP floats.
// ---------------------------------------------------------------------------
__global__ __launch_bounds__(128) void main_kernel(
    const float* __restrict__ xyz, const int* __restrict__ inds,
    const float* __restrict__ G,
    const float* __restrict__ w0x, const float* __restrict__ s0v, const float* __restrict__ t0v,
    const float* __restrict__ wl1, const float* __restrict__ s1v, const float* __restrict__ t1v,
    const float* __restrict__ wl2, const float* __restrict__ s2v, const float* __restrict__ t2v,
    const float* __restrict__ fl1, const float* __restrict__ fs1, const float* __restrict__ ft1,
    const float* __restrict__ fl2, const float* __restrict__ fs2, const float* __restrict__ ft2,
    const float* __restrict__ fl3, const float* __restrict__ b3, float* __restrict__ out)
{
  __shared__ __align__(16) float xt[2][NH * RP];   // 20 KB (2 waves)
  __shared__ float gxs[2][NS][3];
  __shared__ int   idxs[2][NS];

  const int w    = threadIdx.x >> 6;
  const int lane = threadIdx.x & 63;
  const int bid  = blockIdx.x * 2 + w;            // == b*NP + p
  const int b = bid >> 8;
  const int p = bid & 255;
  const int og = lane & 31;
  const int jg = lane >> 5;
  const int joff = jg * 8;

  const float* xb = xyz + b * NPTS * 3;
  float* xs = &xt[w][0];

  // ---- ball query (bit-identical to reference), one wave ----
  {
    const int ci = inds[bid];
    const float cx = xb[ci * 3 + 0], cy = xb[ci * 3 + 1], cz = xb[ci * 3 + 2];
    float nq;
    {
#pragma clang fp contract(off)
      nq = (cx * cx + cy * cy) + cz * cz;
    }
    const float R2 = 0.09f;
    unsigned mask = 0;
    int cnt = 0, firstn = NPTS;
    for (int j = 0; j < 16; ++j) {
#pragma clang fp contract(off)
      int n = lane * 16 + j;   // lane-major: global order == lexicographic
      float x = xb[n * 3 + 0], y = xb[n * 3 + 1], z = xb[n * 3 + 2];
      float nx = (x * x + y * y) + z * z;
      float dt = (cx * x + cy * y) + cz * z;
      float d2 = (nq + nx) - 2.0f * dt;
      if (d2 < R2) { mask |= 1u << j; ++cnt; if (firstn == NPTS) firstn = n; }
    }
    int inc = cnt;
    for (int off = 1; off < 64; off <<= 1) {
      int v = __shfl_up(inc, off);
      if (lane >= off) inc += v;
    }
    int rank  = inc - cnt;
    int total = __shfl(inc, 63);
    for (int j = 0; j < 16; ++j) {
      if (mask & (1u << j)) {
        if (rank < NS) {
          int n = lane * 16 + j;
          idxs[w][rank] = n;
          float x = xb[n * 3 + 0], y = xb[n * 3 + 1], z = xb[n * 3 + 2];
          gxs[w][rank][0] = (x - cx) / 0.3f;
          gxs[w][rank][1] = (y - cy) / 0.3f;
          gxs[w][rank][2] = (z - cz) / 0.3f;
        }
        ++rank;
      }
    }
    int fmin = firstn;
    for (int off2 = 32; off2 > 0; off2 >>= 1) {
      int ov = __shfl_xor(fmin, off2);
      fmin = min(fmin, ov);
    }
    if (lane < NS && lane >= total) {
      idxs[w][lane] = fmin;
      float x = xb[fmin * 3 + 0], y = xb[fmin * 3 + 1], z = xb[fmin * 3 + 2];
      gxs[w][lane][0] = (x - cx) / 0.3f;
      gxs[w][lane][1] = (y - cy) / 0.3f;
      gxs[w][lane][2] = (z - cz) / 0.3f;
    }
  }

  // ---- L0: lane computes x1 rows (lane) and (lane+64) ----
  {
    const float wa0 = w0x[lane],      wb0 = w0x[128 + lane],      wc0 = w0x[256 + lane];
    const float wa1 = w0x[lane + 64], wb1 = w0x[128 + lane + 64], wc1 = w0x[256 + lane + 64];
    const float ss0 = s0v[lane], tt0 = t0v[lane];
    const float ss1 = s0v[lane + 64], tt1 = t0v[lane + 64];
    float r0[16], r1[16];
#pragma unroll
    for (int j = 0; j < 16; ++j) {
      int nj = idxs[w][j];
      float gx = gxs[w][j][0], gy = gxs[w][j][1], gz = gxs[w][j][2];
      const float* gp = G + (b * NPTS + nj) * NH;
      float g0 = gp[lane], g1 = gp[lane + 64];
      float y0 = fmaf(wa0, gx, fmaf(wb0, gy, fmaf(wc0, gz, g0)));
      float y1 = fmaf(wa1, gx, fmaf(wb1, gy, fmaf(wc1, gz, g1)));
      r0[j] = fmaxf(fmaf(y0, ss0, tt0), 0.0f);
      r1[j] = fmaxf(fmaf(y1, ss1, tt1), 0.0f);
    }
    float* rowA = xs + lane * RP;
    float* rowB = xs + (lane + 64) * RP;
#pragma unroll
    for (int q = 0; q < 4; ++q) {
      reinterpret_cast<float4*>(rowA)[q] =
          make_float4(r0[4 * q], r0[4 * q + 1], r0[4 * q + 2], r0[4 * q + 3]);
      reinterpret_cast<float4*>(rowB)[q] =
          make_float4(r1[4 * q], r1[4 * q + 1], r1[4 * q + 2], r1[4 * q + 3]);
    }
  }

  float acc[4][8];

  // ---- L1: lane computes o = og+32k, j in [joff, joff+8) over full c ----
#pragma unroll
  for (int k = 0; k < 4; ++k)
#pragma unroll
    for (int nn = 0; nn < 8; ++nn) acc[k][nn] = 0.0f;
#pragma unroll 2
  for (int c = 0; c < NH; ++c) {
    const float4 wq = *reinterpret_cast<const float4*>(wl1 + (c * 32 + og) * 4);
    const float* row = xs + c * RP + joff;
    const float4 xa = reinterpret_cast<const float4*>(row)[0];
    const float4 xb4 = reinterpret_cast<const float4*>(row)[1];
    const float wk[4] = {wq.x, wq.y, wq.z, wq.w};
    const float xr[8] = {xa.x, xa.y, xa.z, xa.w, xb4.x, xb4.y, xb4.z, xb4.w};
#pragma unroll
    for (int k = 0; k < 4; ++k)
#pragma unroll
      for (int nn = 0; nn < 8; ++nn)
        acc[k][nn] = fmaf(wk[k], xr[nn], acc[k][nn]);
  }
  // BN+ReLU, write x2 (all reads of x1 done in-wave before these writes land)
#pragma unroll
  for (int k = 0; k < 4; ++k) {
    int o = og + 32 * k;
    const float ss = s1v[o], tt = t1v[o];
    float r[8];
#pragma unroll
    for (int nn = 0; nn < 8; ++nn) r[nn] = fmaxf(fmaf(acc[k][nn], ss, tt), 0.0f);
    float* row = xs + o * RP + joff;
    reinterpret_cast<float4*>(row)[0] = make_float4(r[0], r[1], r[2], r[3]);
    reinterpret_cast<float4*>(row)[1] = make_float4(r[4], r[5], r[6], r[7]);
  }

  // ---- L2 + maxpool ----
#pragma unroll
  for (int k = 0; k < 4; ++k)
#pragma unroll
    for (int nn = 0; nn < 8; ++nn) acc[k][nn] = 0.0f;
#pragma unroll 2
  for (int c = 0; c < NH; ++c) {
    const float4 wq = *reinterpret_cast<const float4*>(wl2 + (c * 32 + og) * 4);
    const float* row = xs + c * RP + joff;
    const float4 xa = reinterpret_cast<const float4*>(row)[0];
    const float4 xb4 = reinterpret_cast<const float4*>(row)[1];
    const float wk[4] = {wq.x, wq.y, wq.z, wq.w};
    const float xr[8] = {xa.x, xa.y, xa.z, xa.w, xb4.x, xb4.y, xb4.z, xb4.w};
#pragma unroll
    for (int k = 0; k < 4; ++k)
#pragma unroll
      for (int nn = 0; nn < 8; ++nn)
        acc[k][nn] = fmaf(wk[k], xr[nn], acc[k][nn]);
  }
  // BN+ReLU+max over j (8 local + cross-jg via shfl); f -> xs[0..127]
#pragma unroll
  for (int k = 0; k < 4; ++k) {
    int o = og + 32 * k;
    const float ss = s2v[o], tt = t2v[o];
    float fo = 0.0f;
#pragma unroll
    for (int nn = 0; nn < 8; ++nn)
      fo = fmaxf(fo, fmaxf(fmaf(acc[k][nn], ss, tt), 0.0f));
    fo = fmaxf(fo, __shfl_xor(fo, 32));
    if (jg == 0) xs[o] = fo;
  }

  const int cb = jg * 64;   // c-split for FC stages

  // ---- FC1: h -> xs[128..255] ----
  {
    float h[4] = {0.0f, 0.0f, 0.0f, 0.0f};
#pragma unroll 4
    for (int cl = 0; cl < 64; ++cl) {
      int c = cb + cl;
      const float fv = xs[c];
      const float4 wq = *reinterpret_cast<const float4*>(fl1 + (c * 32 + og) * 4);
      h[0] = fmaf(wq.x, fv, h[0]);
      h[1] = fmaf(wq.y, fv, h[1]);
      h[2] = fmaf(wq.z, fv, h[2]);
      h[3] = fmaf(wq.w, fv, h[3]);
    }
#pragma unroll
    for (int k = 0; k < 4; ++k) {
      h[k] += __shfl_xor(h[k], 32);
      int o = og + 32 * k;
      if (jg == 0) xs[128 + o] = fmaxf(fmaf(h[k], fs1[o], ft1[o]), 0.0f);
    }
  }

  // ---- FC2: f2 -> xs[0..127] ----
  {
    float h[4] = {0.0f, 0.0f, 0.0f, 0.0f};
#pragma unroll 4
    for (int cl = 0; cl < 64; ++cl) {
      int c = cb + cl;
      const float fv = xs[128 + c];
      const float4 wq = *reinterpret_cast<const float4*>(fl2 + (c * 32 + og) * 4);
      h[0] = fmaf(wq.x, fv, h[0]);
      h[1] = fmaf(wq.y, fv, h[1]);
      h[2] = fmaf(wq.z, fv, h[2]);
      h[3] = fmaf(wq.w, fv, h[3]);
    }
#pragma unroll
    for (int k = 0; k < 4; ++k) {
      h[k] += __shfl_xor(h[k], 32);
      int o = og + 32 * k;
      if (jg == 0) xs[o] = fmaxf(fmaf(h[k], fs2[o], ft2[o]), 0.0f);
    }
  }

  // ---- FC3 ----
  {
    float h[4] = {0.0f, 0.0f, 0.0f, 0.0f};
#pragma unroll 4
    for (int cl = 0; cl < 64; ++cl) {
      int c = cb + cl;
      const float fv = xs[c];
      const float4 wq = *reinterpret_cast<const float4*>(fl3 + (c * 32 + og) * 4);
      h[0] = fmaf(wq.x, fv, h[0]);
      h[1] = fmaf(wq.y, fv, h[1]);
      h[2] = fmaf(wq.z, fv, h[2]);
      h[3] = fmaf(wq.w, fv, h[3]);
    }
#pragma unroll
    for (int k = 0; k < 4; ++k) {
      h[k] += __shfl_xor(h[k], 32);
      int o = og + 32 * k;
      if (jg == 0 && o < NOUT) out[(b * NOUT + o) * NP + p] = h[k] + b3[o];
    }
  }
}

extern "C" void kernel_launch(void* const* d_in, const int* in_sizes, int n_in,
                              void* d_out, int out_size, void* d_ws, size_t ws_size,
                              hipStream_t stream) {
  const float* xyz      = (const float*)d_in[0];
  const float* features = (const float*)d_in[1];
  const float* sa_w0 = (const float*)d_in[2];
  const float* sa_s0 = (const float*)d_in[3];
  const float* sa_t0 = (const float*)d_in[4];
  const float* sa_w1 = (const float*)d_in[5];
  const float* sa_s1 = (const float*)d_in[6];
  const float* sa_t1 = (const float*)d_in[7];
  const float* sa_w2 = (const float*)d_in[8];
  const float* sa_s2 = (const float*)d_in[9];
  const float* sa_t2 = (const float*)d_in[10];
  const float* fc_w1 = (const float*)d_in[11];
  const float* fc_s1 = (const float*)d_in[12];
  const float* fc_t1 = (const float*)d_in[13];
  const float* fc_w2 = (const float*)d_in[14];
  const float* fc_s2 = (const float*)d_in[15];
  const float* fc_t2 = (const float*)d_in[16];
  const float* fc_w3 = (const float*)d_in[17];
  const float* fc_b3 = (const float*)d_in[18];
  float* out = (float*)d_out;

  char* ws = (char*)d_ws;
  int* inds = (int*)ws;            ws += (size_t)NB * NP * sizeof(int);
  float* w0l  = (float*)ws;        ws += (size_t)256 * 128 * sizeof(float);
  float* w0x  = (float*)ws;        ws += (size_t)3 * 128 * sizeof(float);
  float* wl1  = (float*)ws;        ws += (size_t)128 * 128 * sizeof(float);
  float* wl2  = (float*)ws;        ws += (size_t)128 * 128 * sizeof(float);
  float* fl1  = (float*)ws;        ws += (size_t)128 * 128 * sizeof(float);
  float* fl2  = (float*)ws;        ws += (size_t)128 * 128 * sizeof(float);
  float* fl3  = (float*)ws;        ws += (size_t)128 * 128 * sizeof(float);
  float* G    = (float*)ws;        ws += (size_t)NB * NPTS * NH * sizeof(float);

  prep_kernel<<<128, 256, 0, stream>>>(sa_w0, sa_w1, sa_w2, fc_w1, fc_w2, fc_w3,
                                       w0l, w0x, wl1, wl2, fl1, fl2, fl3);
  fused_fps_gfeat_kernel<<<NB + NB * (NPTS / 16), 64, 0, stream>>>(
      xyz, inds, features, w0l, G);
  main_kernel<<<NB * NP / 2, 128, 0, stream>>>(
      xyz, inds, G,
      w0x, sa_s0, sa_t0,
      wl1, sa_s1, sa_t1,
      wl2, sa_s2, sa_t2,
      fl1, fc_s1, fc_t1,
      fl2, fc_s2, fc_t2,
      fl3, fc_b3, out);
}

// Round 9
// 344.065 us; speedup vs baseline: 1.3837x; 1.1392x over previous
//
#include <hip/hip_runtime.h>

#define NB 32
#define NPTS 1024
#define NP 256
#define NS 16
#define NC 256
#define NH 128
#define NOUT 97
#define RP 20   // padded LDS row stride (floats): 80B, 16B-aligned

// ---------------------------------------------------------------------------
// Prep. Two lane-split weight layouts:
//   w0l[(c*32+og)*4+k]  = sa_w0[og+32k][3+c]   (gfeat: 32 o-groups x 4)
//   wl*[(c*16+og)*8+k]  = W[og+16k][c]         (main:  16 o-groups x 8)
// ---------------------------------------------------------------------------
__global__ __launch_bounds__(256) void prep_kernel(
    const float* __restrict__ sa_w0, const float* __restrict__ sa_w1,
    const float* __restrict__ sa_w2, const float* __restrict__ fc_w1,
    const float* __restrict__ fc_w2, const float* __restrict__ fc_w3,
    float* __restrict__ w0l, float* __restrict__ w0x,
    float* __restrict__ wl1, float* __restrict__ wl2,
    float* __restrict__ fl1, float* __restrict__ fl2,
    float* __restrict__ fl3)
{
  int t = blockIdx.x * 256 + threadIdx.x;
  if (t >= 256 * 128) return;
  int c = t >> 7, o = t & 127;
  w0l[(c * 32 + (o & 31)) * 4 + (o >> 5)] = sa_w0[o * 259 + 3 + c];
  if (c < 3) w0x[c * 128 + o] = sa_w0[o * 259 + c];
  if (c < 128) {
    int qi = (c * 16 + (o & 15)) * 8 + (o >> 4);
    wl1[qi] = sa_w1[o * 128 + c];
    wl2[qi] = sa_w2[o * 128 + c];
    fl1[qi] = fc_w1[o * 128 + c];
    fl2[qi] = fc_w2[o * 128 + c];
    fl3[qi] = (o < NOUT) ? fc_w3[o * 128 + c] : 0.0f;
  }
}

// DPP reduction ladder steps (16-lane rows): row_shr:1/2/4/8, bcast15, bcast31
template <int CTRL>
__device__ __forceinline__ float dpp_fmax(float v) {
  float o = __int_as_float(
      __builtin_amdgcn_mov_dpp(__float_as_int(v), CTRL, 0xF, 0xF, true));
  return fmaxf(v, o);   // bound_ctrl: invalid lanes -> 0; v >= 0 so identity
}
template <int CTRL>
__device__ __forceinline__ unsigned dpp_umax(unsigned v) {
  unsigned o = (unsigned)__builtin_amdgcn_mov_dpp((int)v, CTRL, 0xF, 0xF, true);
  return v > o ? v : o;
}

// ---------------------------------------------------------------------------
// Fused FPS + gfeat, 64-thread (1-wave) blocks.
//   blocks [0, NB):       FPS. All 48 coords + dist in regs; LDS only for the
//                         uniform centroid lookup. Argmax = pure-VALU DPP
//                         ladder (no ds_swizzle/shfl on the serial chain).
//   blocks [NB, NB+2048): gfeat, j-split-2: acc[4][8], full-c per lane.
// ---------------------------------------------------------------------------
__global__ __launch_bounds__(64) void fused_fps_gfeat_kernel(
    const float* __restrict__ xyz, int* __restrict__ inds,
    const float* __restrict__ features, const float* __restrict__ w0l,
    float* __restrict__ G)
{
  __shared__ __align__(16) float smem[NC * RP];   // 20 KB
  const int lane = threadIdx.x;

  if (blockIdx.x < NB) {
    // ------------------------- FPS -------------------------
    const int b = blockIdx.x;
    const float* xb = xyz + b * NPTS * 3;
    float* s_x = smem;
    float* s_y = smem + NPTS;
    float* s_z = smem + 2 * NPTS;
    float px[16], py[16], pz[16], dist[16];
    const float4* src = reinterpret_cast<const float4*>(xb + lane * 48);
#pragma unroll
    for (int q = 0; q < 4; ++q) {
      float4 v0 = src[3 * q], v1 = src[3 * q + 1], v2 = src[3 * q + 2];
      const float xv[4] = {v0.x, v0.w, v1.z, v2.y};
      const float yv[4] = {v0.y, v1.x, v1.w, v2.z};
      const float zv[4] = {v0.z, v1.y, v2.x, v2.w};
#pragma unroll
      for (int t = 0; t < 4; ++t) {
        int j = 4 * q + t;
        px[j] = xv[t]; py[j] = yv[t]; pz[j] = zv[t];
        s_x[lane * 16 + j] = xv[t];
        s_y[lane * 16 + j] = yv[t];
        s_z[lane * 16 + j] = zv[t];
      }
    }
#pragma unroll
    for (int j = 0; j < 16; ++j) dist[j] = 1e10f;
    int far = 0;
    for (int i = 0; i < NP; ++i) {
      if (lane == 0) inds[b * NP + i] = far;
      float cx = s_x[far], cy = s_y[far], cz = s_z[far];   // uniform broadcast
      float bv = -1.0f; int bi = 0;
#pragma unroll
      for (int j = 0; j < 16; ++j) {
#pragma clang fp contract(off)
        float dx = px[j] - cx;
        float dy = py[j] - cy;
        float dz = pz[j] - cz;
        float d = (dx * dx + dy * dy) + dz * dz;
        float nd = fminf(dist[j], d);
        dist[j] = nd;
        if (nd > bv) { bv = nd; bi = lane * 16 + j; }   // ascending j: first max
      }
      // global max of bv (pure VALU DPP ladder), lane 63 holds result
      float r = bv;
      r = dpp_fmax<0x111>(r);   // row_shr:1
      r = dpp_fmax<0x112>(r);   // row_shr:2
      r = dpp_fmax<0x114>(r);   // row_shr:4
      r = dpp_fmax<0x118>(r);   // row_shr:8
      r = dpp_fmax<0x142>(r);   // row_bcast:15
      r = dpp_fmax<0x143>(r);   // row_bcast:31
      float gmax = __int_as_float(__builtin_amdgcn_readlane(__float_as_int(r), 63));
      // first (min-index) lane value achieving gmax: max of ~idx among cands
      unsigned cand = (bv == gmax) ? ~(unsigned)bi : 0u;
      cand = dpp_umax<0x111>(cand);
      cand = dpp_umax<0x112>(cand);
      cand = dpp_umax<0x114>(cand);
      cand = dpp_umax<0x118>(cand);
      cand = dpp_umax<0x142>(cand);
      cand = dpp_umax<0x143>(cand);
      unsigned cmax = (unsigned)__builtin_amdgcn_readlane((int)cand, 63);
      far = (int)(~cmax);
    }
    return;
  }

  // ------------------------- gfeat (j-split-2) -------------------------
  const int blk = blockIdx.x - NB;
  const int b  = blk >> 6;
  const int n0 = (blk & 63) * 16;
  const int og = lane & 31;
  const int jg = lane >> 5;
  const int joff = jg * 8;
  const float* fb = features + b * NC * NPTS;
#pragma unroll
  for (int r = 0; r < 4; ++r) {
    int c = r * 64 + lane;
    const float4* s4 = reinterpret_cast<const float4*>(fb + c * NPTS + n0);
    float4 v0 = s4[0], v1 = s4[1], v2 = s4[2], v3 = s4[3];
    float* row = smem + c * RP;
    reinterpret_cast<float4*>(row)[0] = v0;
    reinterpret_cast<float4*>(row)[1] = v1;
    reinterpret_cast<float4*>(row)[2] = v2;
    reinterpret_cast<float4*>(row)[3] = v3;
  }
  // single wave: LDS write->read ordered in-wave by lgkmcnt.
  float acc[4][8];
#pragma unroll
  for (int k = 0; k < 4; ++k)
#pragma unroll
    for (int nn = 0; nn < 8; ++nn) acc[k][nn] = 0.0f;
#pragma unroll 2
  for (int c = 0; c < NC; ++c) {
    const float4 wq = *reinterpret_cast<const float4*>(w0l + (c * 32 + og) * 4);
    const float* row = smem + c * RP + joff;
    const float4 xa = reinterpret_cast<const float4*>(row)[0];
    const float4 xb4 = reinterpret_cast<const float4*>(row)[1];
    const float wk[4] = {wq.x, wq.y, wq.z, wq.w};
    const float xr[8] = {xa.x, xa.y, xa.z, xa.w, xb4.x, xb4.y, xb4.z, xb4.w};
#pragma unroll
    for (int k = 0; k < 4; ++k)
#pragma unroll
      for (int nn = 0; nn < 8; ++nn)
        acc[k][nn] = fmaf(wk[k], xr[nn], acc[k][nn]);
  }
#pragma unroll
  for (int k = 0; k < 4; ++k) {
    int o = og + 32 * k;
    float* gp = G + ((size_t)(b * NPTS + n0 + joff)) * NH + o;
#pragma unroll
    for (int nn = 0; nn < 8; ++nn) gp[nn * NH] = acc[k][nn];
  }
}

// ---------------------------------------------------------------------------
// Main kernel: 128-thread blocks = 2 independent waves, each wave owns one
// (b,p) tile. No __syncthreads (wave-lockstep LDS ordering).
// j-split-4: lane=(og=lane&15, jg=lane>>4); acc[8][4] (32 regs), full c per
// lane, ONE ds_read_b128 per c (halved LDS-pipe load). Maxpool/FC merge via
// shfl_xor(16)+shfl_xor(32).
// ---------------------------------------------------------------------------
__global__ __launch_bounds__(128) void main_kernel(
    const float* __restrict__ xyz, const int* __restrict__ inds,
    const float* __restrict__ G,
    const float* __restrict__ w0x, const float* __restrict__ s0v, const float* __restrict__ t0v,
    const float* __restrict__ wl1, const float* __restrict__ s1v, const float* __restrict__ t1v,
    const float* __restrict__ wl2, const float* __restrict__ s2v, const float* __restrict__ t2v,
    const float* __restrict__ fl1, const float* __restrict__ fs1, const float* __restrict__ ft1,
    const float* __restrict__ fl2, const float* __restrict__ fs2, const float* __restrict__ ft2,
    const float* __restrict__ fl3, const float* __restrict__ b3, float* __restrict__ out)
{
  __shared__ __align__(16) float xt[2][NH * RP];   // 20 KB (2 waves)
  __shared__ float gxs[2][NS][3];
  __shared__ int   idxs[2][NS];

  const int w    = threadIdx.x >> 6;
  const int lane = threadIdx.x & 63;
  const int bid  = blockIdx.x * 2 + w;            // == b*NP + p
  const int b = bid >> 8;
  const int p = bid & 255;
  const int og = lane & 15;
  const int jg = lane >> 4;                        // 0..3
  const int joff = jg * 4;

  const float* xb = xyz + b * NPTS * 3;
  float* xs = &xt[w][0];

  // ---- ball query (bit-identical to reference), one wave ----
  {
    const int ci = inds[bid];
    const float cx = xb[ci * 3 + 0], cy = xb[ci * 3 + 1], cz = xb[ci * 3 + 2];
    float nq;
    {
#pragma clang fp contract(off)
      nq = (cx * cx + cy * cy) + cz * cz;
    }
    const float R2 = 0.09f;
    unsigned mask = 0;
    int cnt = 0, firstn = NPTS;
    for (int j = 0; j < 16; ++j) {
#pragma clang fp contract(off)
      int n = lane * 16 + j;   // lane-major: global order == lexicographic
      float x = xb[n * 3 + 0], y = xb[n * 3 + 1], z = xb[n * 3 + 2];
      float nx = (x * x + y * y) + z * z;
      float dt = (cx * x + cy * y) + cz * z;
      float d2 = (nq + nx) - 2.0f * dt;
      if (d2 < R2) { mask |= 1u << j; ++cnt; if (firstn == NPTS) firstn = n; }
    }
    int inc = cnt;
    for (int off = 1; off < 64; off <<= 1) {
      int v = __shfl_up(inc, off);
      if (lane >= off) inc += v;
    }
    int rank  = inc - cnt;
    int total = __shfl(inc, 63);
    for (int j = 0; j < 16; ++j) {
      if (mask & (1u << j)) {
        if (rank < NS) {
          int n = lane * 16 + j;
          idxs[w][rank] = n;
          float x = xb[n * 3 + 0], y = xb[n * 3 + 1], z = xb[n * 3 + 2];
          gxs[w][rank][0] = (x - cx) / 0.3f;
          gxs[w][rank][1] = (y - cy) / 0.3f;
          gxs[w][rank][2] = (z - cz) / 0.3f;
        }
        ++rank;
      }
    }
    int fmin = firstn;
    for (int off2 = 32; off2 > 0; off2 >>= 1) {
      int ov = __shfl_xor(fmin, off2);
      fmin = min(fmin, ov);
    }
    if (lane < NS && lane >= total) {
      idxs[w][lane] = fmin;
      float x = xb[fmin * 3 + 0], y = xb[fmin * 3 + 1], z = xb[fmin * 3 + 2];
      gxs[w][lane][0] = (x - cx) / 0.3f;
      gxs[w][lane][1] = (y - cy) / 0.3f;
      gxs[w][lane][2] = (z - cz) / 0.3f;
    }
  }

  // ---- L0: lane computes x1 rows (lane) and (lane+64) ----
  {
    const float wa0 = w0x[lane],      wb0 = w0x[128 + lane],      wc0 = w0x[256 + lane];
    const float wa1 = w0x[lane + 64], wb1 = w0x[128 + lane + 64], wc1 = w0x[256 + lane + 64];
    const float ss0 = s0v[lane], tt0 = t0v[lane];
    const float ss1 = s0v[lane + 64], tt1 = t0v[lane + 64];
    float r0[16], r1[16];
#pragma unroll
    for (int j = 0; j < 16; ++j) {
      int nj = idxs[w][j];
      float gx = gxs[w][j][0], gy = gxs[w][j][1], gz = gxs[w][j][2];
      const float* gp = G + (b * NPTS + nj) * NH;
      float g0 = gp[lane], g1 = gp[lane + 64];
      float y0 = fmaf(wa0, gx, fmaf(wb0, gy, fmaf(wc0, gz, g0)));
      float y1 = fmaf(wa1, gx, fmaf(wb1, gy, fmaf(wc1, gz, g1)));
      r0[j] = fmaxf(fmaf(y0, ss0, tt0), 0.0f);
      r1[j] = fmaxf(fmaf(y1, ss1, tt1), 0.0f);
    }
    float* rowA = xs + lane * RP;
    float* rowB = xs + (lane + 64) * RP;
#pragma unroll
    for (int q = 0; q < 4; ++q) {
      reinterpret_cast<float4*>(rowA)[q] =
          make_float4(r0[4 * q], r0[4 * q + 1], r0[4 * q + 2], r0[4 * q + 3]);
      reinterpret_cast<float4*>(rowB)[q] =
          make_float4(r1[4 * q], r1[4 * q + 1], r1[4 * q + 2], r1[4 * q + 3]);
    }
  }

  float acc[8][4];

  // ---- L1: lane computes o = og+16k (k 0..7), j in [joff, joff+4) ----
#pragma unroll
  for (int k = 0; k < 8; ++k)
#pragma unroll
    for (int nn = 0; nn < 4; ++nn) acc[k][nn] = 0.0f;
#pragma unroll 2
  for (int c = 0; c < NH; ++c) {
    const float* wp = wl1 + (c * 16 + og) * 8;
    const float4 wqa = reinterpret_cast<const float4*>(wp)[0];
    const float4 wqb = reinterpret_cast<const float4*>(wp)[1];
    const float4 xv = *reinterpret_cast<const float4*>(xs + c * RP + joff);
    const float wk[8] = {wqa.x, wqa.y, wqa.z, wqa.w, wqb.x, wqb.y, wqb.z, wqb.w};
    const float xr[4] = {xv.x, xv.y, xv.z, xv.w};
#pragma unroll
    for (int k = 0; k < 8; ++k)
#pragma unroll
      for (int nn = 0; nn < 4; ++nn)
        acc[k][nn] = fmaf(wk[k], xr[nn], acc[k][nn]);
  }
  // BN+ReLU, write x2 chunks (all x1 reads complete in-wave before writes)
#pragma unroll
  for (int k = 0; k < 8; ++k) {
    int o = og + 16 * k;
    const float ss = s1v[o], tt = t1v[o];
    float4 r;
    r.x = fmaxf(fmaf(acc[k][0], ss, tt), 0.0f);
    r.y = fmaxf(fmaf(acc[k][1], ss, tt), 0.0f);
    r.z = fmaxf(fmaf(acc[k][2], ss, tt), 0.0f);
    r.w = fmaxf(fmaf(acc[k][3], ss, tt), 0.0f);
    *reinterpret_cast<float4*>(xs + o * RP + joff) = r;
  }

  // ---- L2 + maxpool ----
#pragma unroll
  for (int k = 0; k < 8; ++k)
#pragma unroll
    for (int nn = 0; nn < 4; ++nn) acc[k][nn] = 0.0f;
#pragma unroll 2
  for (int c = 0; c < NH; ++c) {
    const float* wp = wl2 + (c * 16 + og) * 8;
    const float4 wqa = reinterpret_cast<const float4*>(wp)[0];
    const float4 wqb = reinterpret_cast<const float4*>(wp)[1];
    const float4 xv = *reinterpret_cast<const float4*>(xs + c * RP + joff);
    const float wk[8] = {wqa.x, wqa.y, wqa.z, wqa.w, wqb.x, wqb.y, wqb.z, wqb.w};
    const float xr[4] = {xv.x, xv.y, xv.z, xv.w};
#pragma unroll
    for (int k = 0; k < 8; ++k)
#pragma unroll
      for (int nn = 0; nn < 4; ++nn)
        acc[k][nn] = fmaf(wk[k], xr[nn], acc[k][nn]);
  }
  // BN+ReLU+max over local 4 j's, then cross-jg; f -> xs[0..127]
#pragma unroll
  for (int k = 0; k < 8; ++k) {
    int o = og + 16 * k;
    const float ss = s2v[o], tt = t2v[o];
    float fo = 0.0f;
#pragma unroll
    for (int nn = 0; nn < 4; ++nn)
      fo = fmaxf(fo, fmaxf(fmaf(acc[k][nn], ss, tt), 0.0f));
    fo = fmaxf(fo, __shfl_xor(fo, 16));
    fo = fmaxf(fo, __shfl_xor(fo, 32));
    if (jg == 0) xs[o] = fo;
  }

  const int cb = jg * 32;   // c-split-4 for FC stages

  // ---- FC1: h -> xs[128..255] ----
  {
    float h[8] = {0, 0, 0, 0, 0, 0, 0, 0};
#pragma unroll 4
    for (int cl = 0; cl < 32; ++cl) {
      int c = cb + cl;
      const float fv = xs[c];
      const float* wp = fl1 + (c * 16 + og) * 8;
      const float4 wqa = reinterpret_cast<const float4*>(wp)[0];
      const float4 wqb = reinterpret_cast<const float4*>(wp)[1];
      h[0] = fmaf(wqa.x, fv, h[0]); h[1] = fmaf(wqa.y, fv, h[1]);
      h[2] = fmaf(wqa.z, fv, h[2]); h[3] = fmaf(wqa.w, fv, h[3]);
      h[4] = fmaf(wqb.x, fv, h[4]); h[5] = fmaf(wqb.y, fv, h[5]);
      h[6] = fmaf(wqb.z, fv, h[6]); h[7] = fmaf(wqb.w, fv, h[7]);
    }
#pragma unroll
    for (int k = 0; k < 8; ++k) {
      h[k] += __shfl_xor(h[k], 16);
      h[k] += __shfl_xor(h[k], 32);
      int o = og + 16 * k;
      if (jg == 0) xs[128 + o] = fmaxf(fmaf(h[k], fs1[o], ft1[o]), 0.0f);
    }
  }

  // ---- FC2: f2 -> xs[0..127] ----
  {
    float h[8] = {0, 0, 0, 0, 0, 0, 0, 0};
#pragma unroll 4
    for (int cl = 0; cl < 32; ++cl) {
      int c = cb + cl;
      const float fv = xs[128 + c];
      const float* wp = fl2 + (c * 16 + og) * 8;
      const float4 wqa = reinterpret_cast<const float4*>(wp)[0];
      const float4 wqb = reinterpret_cast<const float4*>(wp)[1];
      h[0] = fmaf(wqa.x, fv, h[0]); h[1] = fmaf(wqa.y, fv, h[1]);
      h[2] = fmaf(wqa.z, fv, h[2]); h[3] = fmaf(wqa.w, fv, h[3]);
      h[4] = fmaf(wqb.x, fv, h[4]); h[5] = fmaf(wqb.y, fv, h[5]);
      h[6] = fmaf(wqb.z, fv, h[6]); h[7] = fmaf(wqb.w, fv, h[7]);
    }
#pragma unroll
    for (int k = 0; k < 8; ++k) {
      h[k] += __shfl_xor(h[k], 16);
      h[k] += __shfl_xor(h[k], 32);
      int o = og + 16 * k;
      if (jg == 0) xs[o] = fmaxf(fmaf(h[k], fs2[o], ft2[o]), 0.0f);
    }
  }

  // ---- FC3 ----
  {
    float h[8] = {0, 0, 0, 0, 0, 0, 0, 0};
#pragma unroll 4
    for (int cl = 0; cl < 32; ++cl) {
      int c = cb + cl;
      const float fv = xs[c];
      const float* wp = fl3 + (c * 16 + og) * 8;
      const float4 wqa = reinterpret_cast<const float4*>(wp)[0];
      const float4 wqb = reinterpret_cast<const float4*>(wp)[1];
      h[0] = fmaf(wqa.x, fv, h[0]); h[1] = fmaf(wqa.y, fv, h[1]);
      h[2] = fmaf(wqa.z, fv, h[2]); h[3] = fmaf(wqa.w, fv, h[3]);
      h[4] = fmaf(wqb.x, fv, h[4]); h[5] = fmaf(wqb.y, fv, h[5]);
      h[6] = fmaf(wqb.z, fv, h[6]); h[7] = fmaf(wqb.w, fv, h[7]);
    }
#pragma unroll
    for (int k = 0; k < 8; ++k) {
      h[k] += __shfl_xor(h[k], 16);
      h[k] += __shfl_xor(h[k], 32);
      int o = og + 16 * k;
      if (jg == 0 && o < NOUT) out[(b * NOUT + o) * NP + p] = h[k] + b3[o];
    }
  }
}

extern "C" void kernel_launch(void* const* d_in, const int* in_sizes, int n_in,
                              void* d_out, int out_size, void* d_ws, size_t ws_size,
                              hipStream_t stream) {
  const float* xyz      = (const float*)d_in[0];
  const float* features = (const float*)d_in[1];
  const float* sa_w0 = (const float*)d_in[2];
  const float* sa_s0 = (const float*)d_in[3];
  const float* sa_t0 = (const float*)d_in[4];
  const float* sa_w1 = (const float*)d_in[5];
  const float* sa_s1 = (const float*)d_in[6];
  const float* sa_t1 = (const float*)d_in[7];
  const float* sa_w2 = (const float*)d_in[8];
  const float* sa_s2 = (const float*)d_in[9];
  const float* sa_t2 = (const float*)d_in[10];
  const float* fc_w1 = (const float*)d_in[11];
  const float* fc_s1 = (const float*)d_in[12];
  const float* fc_t1 = (const float*)d_in[13];
  const float* fc_w2 = (const float*)d_in[14];
  const float* fc_s2 = (const float*)d_in[15];
  const float* fc_t2 = (const float*)d_in[16];
  const float* fc_w3 = (const float*)d_in[17];
  const float* fc_b3 = (const float*)d_in[18];
  float* out = (float*)d_out;

  char* ws = (char*)d_ws;
  int* inds = (int*)ws;            ws += (size_t)NB * NP * sizeof(int);
  float* w0l  = (float*)ws;        ws += (size_t)256 * 128 * sizeof(float);
  float* w0x  = (float*)ws;        ws += (size_t)3 * 128 * sizeof(float);
  float* wl1  = (float*)ws;        ws += (size_t)128 * 128 * sizeof(float);
  float* wl2  = (float*)ws;        ws += (size_t)128 * 128 * sizeof(float);
  float* fl1  = (float*)ws;        ws += (size_t)128 * 128 * sizeof(float);
  float* fl2  = (float*)ws;        ws += (size_t)128 * 128 * sizeof(float);
  float* fl3  = (float*)ws;        ws += (size_t)128 * 128 * sizeof(float);
  float* G    = (float*)ws;        ws += (size_t)NB * NPTS * NH * sizeof(float);

  prep_kernel<<<128, 256, 0, stream>>>(sa_w0, sa_w1, sa_w2, fc_w1, fc_w2, fc_w3,
                                       w0l, w0x, wl1, wl2, fl1, fl2, fl3);
  fused_fps_gfeat_kernel<<<NB + NB * (NPTS / 16), 64, 0, stream>>>(
      xyz, inds, features, w0l, G);
  main_kernel<<<NB * NP / 2, 128, 0, stream>>>(
      xyz, inds, G,
      w0x, sa_s0, sa_t0,
      wl1, sa_s1, sa_t1,
      wl2, sa_s2, sa_t2,
      fl1, fc_s1, fc_t1,
      fl2, fc_s2, fc_t2,
      fl3, fc_b3, out);
}